// Round 13
// baseline (214.111 us; speedup 1.0000x reference)
//
#include <hip/hip_runtime.h>

#define EPSV 1e-8f
#define PW   34
#define NPIX 1024
#define NA   5
#define NOUT 17
#define NZC  150
#define MAXS 8

// ================= K0: obs-MLP softmax weights + Z2oZ1 collapse =============
__global__ __launch_bounds__(256) void k0_prep(
    const float* __restrict__ obs_in,
    const float* __restrict__ O1_w, const float* __restrict__ O1_b,
    const float* __restrict__ O3_w, const float* __restrict__ O3_b,
    const float* __restrict__ Z1_w, const float* __restrict__ Z1_b,
    const float* __restrict__ Z2_w, const float* __restrict__ Z2_b,
    float* __restrict__ w_all, float* __restrict__ zc, int S)
{
    __shared__ float h[MAXS*NOUT], u[MAXS*NOUT];
    const int tid = threadIdx.x, b = blockIdx.x;
    const int t = tid / NOUT, o = tid % NOUT;
    const bool act = (tid < S*NOUT);

    if (act) {
        const float* ob = obs_in + (b*S + t)*4;
        float hh = O1_b[o];
        #pragma unroll
        for (int k = 0; k < 4; ++k) hh += ob[k] * O1_w[o*4 + k];
        h[tid] = tanhf(hh);
    }
    __syncthreads();
    if (act) {
        float uu = O3_b[o];
        #pragma unroll
        for (int j = 0; j < NOUT; ++j) uu += h[t*NOUT + j] * O3_w[o*NOUT + j];
        u[tid] = uu;
    }
    __syncthreads();
    if (act) {
        float mx = u[t*NOUT];
        #pragma unroll
        for (int j = 1; j < NOUT; ++j) mx = fmaxf(mx, u[t*NOUT + j]);
        float sm = 0.f;
        #pragma unroll
        for (int j = 0; j < NOUT; ++j) sm += expf(u[t*NOUT + j] - mx);
        w_all[(b*MAXS + t)*NOUT + o] = expf(u[tid] - mx) / sm;
    }
    // block 0 additionally computes the collapsed Z conv (170 outputs)
    if (b == 0) {
        for (int j2 = tid; j2 < NOUT*9 + NOUT; j2 += 256) {
            if (j2 < NOUT*9) {
                const int oo = j2 / 9, k = j2 % 9;
                float s = 0.f;
                for (int c = 0; c < NZC; ++c) s += Z2_w[oo*NZC + c] * Z1_w[c*9 + k];
                zc[j2] = s;
            } else {
                const int oo = j2 - NOUT*9;
                float s = Z2_b[oo];
                for (int c = 0; c < NZC; ++c) s += Z2_w[oo*NZC + c] * Z1_b[c];
                zc[j2] = s;
            }
        }
    }
}

// ================= K1: per-pixel R-conv + Z + zo (no serial coupling) =======
// grid = B*4 (one 8-row strip per block), block = 256 (1 px/thread)
__global__ __launch_bounds__(256, 4) void k1_rz(
    const float* __restrict__ map_in,
    const float* __restrict__ R1_w, const float* __restrict__ R1_b,
    const float* __restrict__ R2_w, const float* __restrict__ R2_b,
    const float* __restrict__ w_all, const float* __restrict__ zc,
    float* __restrict__ r_out, float* __restrict__ zo_out, int S)
{
    __shared__ float t0[10*34], t1[10*34];
    const int tid = threadIdx.x;
    const int b = blockIdx.x >> 2, strip = blockIdx.x & 3;
    const int ty = tid >> 5, x = tid & 31;     // ty 0..7
    const int y = strip*8 + ty;
    const int pix = y*32 + x;

    // stage 10x34 zero-padded map tile (both channels)
    for (int i = tid; i < 340; i += 256) {
        const int tr = i / 34, tc = i % 34;
        const int gy = strip*8 - 1 + tr, gx = tc - 1;
        const bool ok = (gy >= 0 && gy < 32 && gx >= 0 && gx < 32);
        t0[i] = ok ? map_in[b*2*NPIX + gy*32 + gx] : 0.f;
        t1[i] = ok ? map_in[b*2*NPIX + NPIX + gy*32 + gx] : 0.f;
    }
    __syncthreads();

    float m0[9], m1[9];
    #pragma unroll
    for (int k = 0; k < 9; ++k) {
        const int off = (ty + k/3)*34 + x + (k%3);
        m0[k] = t0[off]; m1[k] = t1[off];
    }

    // R-conv (R12 2-ch ILP form, measured-neutral but kept)
    float rA[NA], rB[NA];
    #pragma unroll
    for (int a = 0; a < NA; ++a) { rA[a] = R2_b[a]; rB[a] = 0.f; }
    for (int c = 0; c < NZC; c += 2) {
        const float* w1a = R1_w + c*18;
        const float* w1b = w1a + 18;
        float s0 = R1_b[c], s1 = R1_b[c+1];
        #pragma unroll
        for (int k = 0; k < 9; ++k) { s0 += m0[k] * w1a[k];   s1 += m0[k] * w1b[k]; }
        #pragma unroll
        for (int k = 0; k < 9; ++k) { s0 += m1[k] * w1a[9+k]; s1 += m1[k] * w1b[9+k]; }
        s0 = fmaxf(s0, 0.f); s1 = fmaxf(s1, 0.f);
        #pragma unroll
        for (int a = 0; a < NA; ++a) {
            rA[a] += R2_w[a*NZC + c]     * s0;
            rB[a] += R2_w[a*NZC + c + 1] * s1;
        }
    }
    #pragma unroll
    for (int a = 0; a < NA; ++a)
        r_out[(b*NA + a)*NPIX + pix] = rA[a] + rB[a];

    // Z: sigmoid(collapsed conv), normalize, fold against w_t -> zo
    float z[NOUT];
    float zs = 0.f;
    #pragma unroll
    for (int o = 0; o < NOUT; ++o) {
        float s = zc[NOUT*9 + o];
        #pragma unroll
        for (int k = 0; k < 9; ++k) s += m0[k] * zc[o*9 + k];
        const float zz = 1.f / (1.f + expf(-s));
        z[o] = zz; zs += zz;
    }
    const float zn = 1.f / (zs + EPSV);
    for (int t = 0; t < S; ++t) {
        float zo = 0.f;
        #pragma unroll
        for (int o = 0; o < NOUT; ++o) zo += z[o] * w_all[(b*MAXS + t)*NOUT + o];
        zo_out[(b*S + t)*NPIX + pix] = zo * zn;
    }
}

// ================= K2: VI (R5 2-barrier structure) + belief =================
__global__ __launch_bounds__(1024, 4) void k2_vib(
    const float* __restrict__ b0,   const int* __restrict__ act_in,
    const int*   __restrict__ step_p, const int* __restrict__ vik_p,
    const float* __restrict__ Tb_w, const float* __restrict__ Tb_b,
    const float* __restrict__ Tv_w, const float* __restrict__ Tv_b,
    const float* __restrict__ FL_w, const float* __restrict__ FL_b,
    const float* __restrict__ r_in, const float* __restrict__ zo_in,
    float* __restrict__ out, int B)
{
    __shared__ float v_lds[PW*PW], b_lds[PW*PW];
    __shared__ float partials[16][6], sums[6];

    const int tid  = threadIdx.x;
    const int blk  = blockIdx.x;
    const int y    = tid >> 5, x = tid & 31;
    const int pidx = (y + 1) * PW + (x + 1);
    const int lane = tid & 63, wvid = tid >> 6;

    const int S = step_p[0];
    const int K = vik_p[0];

    for (int i = tid; i < PW*PW; i += NPIX) { v_lds[i] = 0.f; b_lds[i] = 0.f; }
    __syncthreads();
    b_lds[pidx] = b0[blk*NPIX + tid];

    // r with Tv bias folded
    float r[NA];
    #pragma unroll
    for (int a = 0; a < NA; ++a)
        r[a] = r_in[(blk*NA + a)*NPIX + tid] + Tv_b[a];

    // value iteration: single buffer, 2 barriers/iter (banked best)
    float q[NA];
    #pragma unroll
    for (int a = 0; a < NA; ++a) q[a] = 0.f;
    for (int it = 0; it < K; ++it) {
        float n[9];
        #pragma unroll
        for (int k = 0; k < 9; ++k) n[k] = v_lds[(y + k/3)*PW + x + (k%3)];
        float vmax = -3.4e38f;
        #pragma unroll
        for (int a = 0; a < NA; ++a) {
            float s = r[a];
            #pragma unroll
            for (int k = 0; k < 9; ++k) s += n[k] * Tv_w[a*9 + k];
            q[a] = s;
            vmax = fmaxf(vmax, s);
        }
        __syncthreads();
        v_lds[pidx] = vmax;
        __syncthreads();
    }

    // belief-propagation timestep loop
    for (int t = 0; t < S; ++t) {
        const int a_t = act_in[blk*S + t];
        float bp = Tb_b[a_t];
        #pragma unroll
        for (int k = 0; k < 9; ++k)
            bp += b_lds[(y + k/3)*PW + x + (k%3)] * Tb_w[a_t*9 + k];

        const float bn = bp * zo_in[(blk*S + t)*NPIX + tid];

        float v6[6];
        v6[5] = bn;
        #pragma unroll
        for (int a = 0; a < NA; ++a) v6[a] = q[a] * bn;
        #pragma unroll
        for (int k = 0; k < 6; ++k) {
            float vv = v6[k];
            for (int off = 32; off > 0; off >>= 1) vv += __shfl_down(vv, off);
            v6[k] = vv;
        }
        if (lane == 0) {
            #pragma unroll
            for (int k = 0; k < 6; ++k) partials[wvid][k] = v6[k];
        }
        __syncthreads();
        if (tid < 6) {
            float s = 0.f;
            for (int w2 = 0; w2 < 16; ++w2) s += partials[w2][tid];
            sums[tid] = s;
        }
        __syncthreads();

        const float inv = 1.f / (sums[5] + EPSV);
        if (tid < NA) {
            float oj = FL_b[tid];
            #pragma unroll
            for (int a = 0; a < NA; ++a) oj += (sums[a] * inv) * FL_w[tid*NA + a];
            out[(t*B + blk)*NA + tid] = oj;
        }
        b_lds[pidx] = bn * inv;
        __syncthreads();
    }

    out[S*B*NA + blk*NPIX + tid] = b_lds[pidx];
}

extern "C" void kernel_launch(void* const* d_in, const int* in_sizes, int n_in,
                              void* d_out, int out_size, void* d_ws, size_t ws_size,
                              hipStream_t stream)
{
    const float* map_in = (const float*)d_in[0];
    const float* b0     = (const float*)d_in[1];
    const int*   act_in = (const int*)  d_in[2];
    const float* obs_in = (const float*)d_in[3];
    const int*   step_p = (const int*)  d_in[5];
    const int*   vik_p  = (const int*)  d_in[6];
    const float* Tb_w = (const float*)d_in[7];
    const float* Tb_b = (const float*)d_in[8];
    const float* Tv_w = (const float*)d_in[9];
    const float* Tv_b = (const float*)d_in[10];
    const float* Z1_w = (const float*)d_in[11];
    const float* Z1_b = (const float*)d_in[12];
    const float* Z2_w = (const float*)d_in[13];
    const float* Z2_b = (const float*)d_in[14];
    const float* O1_w = (const float*)d_in[15];
    const float* O1_b = (const float*)d_in[16];
    const float* O3_w = (const float*)d_in[17];
    const float* O3_b = (const float*)d_in[18];
    const float* R1_w = (const float*)d_in[19];
    const float* R1_b = (const float*)d_in[20];
    const float* R2_w = (const float*)d_in[21];
    const float* R2_b = (const float*)d_in[22];
    const float* FL_w = (const float*)d_in[23];
    const float* FL_b = (const float*)d_in[24];

    const int B = in_sizes[1] / NPIX;     // b0 is (B,32,32)
    const int S = in_sizes[2] / B;        // act_in is (B,S)

    // ws layout (floats): w_all[B*MAXS*NOUT] | zc[192 pad] | r[B*NA*NPIX] | zo[B*S*NPIX]
    float* ws    = (float*)d_ws;
    float* w_all = ws;
    float* zc    = w_all + (size_t)B*MAXS*NOUT;
    float* r_ws  = zc + 192;
    float* zo_ws = r_ws + (size_t)B*NA*NPIX;

    hipLaunchKernelGGL(k0_prep, dim3(B), dim3(256), 0, stream,
        obs_in, O1_w, O1_b, O3_w, O3_b, Z1_w, Z1_b, Z2_w, Z2_b, w_all, zc, S);

    hipLaunchKernelGGL(k1_rz, dim3(B*4), dim3(256), 0, stream,
        map_in, R1_w, R1_b, R2_w, R2_b, w_all, zc, r_ws, zo_ws, S);

    hipLaunchKernelGGL(k2_vib, dim3(B), dim3(1024), 0, stream,
        b0, act_in, step_p, vik_p, Tb_w, Tb_b, Tv_w, Tv_b, FL_w, FL_b,
        r_ws, zo_ws, (float*)d_out, B);
}